// Round 10
// baseline (81.720 us; speedup 1.0000x reference)
//
#include <hip/hip_runtime.h>
#include <cstdint>
#include <cstddef>

// ---------------------------------------------------------------------------
// CosineDistance via exact int8 reconstruction:
//   ref's 9 bit-slice GEMMs == qx (int8) @ qw^T (int8), dequant, 1 - cos.
// R2: removed single-address atomicMax serialization.
// R3-R8: gemm schedule experiments; R9: LDS-transpose quant (coalesced).
// R10: faithful 4-phase template port for the gemm:
//   - phase = {ds_read frags; (stage); barrier; lgkm0; 16 MFMA; barrier}
//     with reads issued BEFORE the leading barrier (latency hides under
//     barrier arrival; other wave on SIMD MFMAs meanwhile, setprio helps)
//   - kt+1 staging spread over phases 0-1; single vmcnt(0) at phase 3
//     waits on >=2-phase-old loads (~free)
//   - every phase drains lgkmcnt(0) pre-trailing-barrier -> ring-2 reuse
//     provably race-free.
// ---------------------------------------------------------------------------

#define D_COLS 1024
#define M_ROWS 4096   // x rows
#define N_ROWS 8192   // weight rows

using i32x4 = __attribute__((ext_vector_type(4))) int;

__device__ __forceinline__ void gload_lds16(const void* g, void* lds) {
  __builtin_amdgcn_global_load_lds(
      (const __attribute__((address_space(1))) uint32_t*)g,
      (__attribute__((address_space(3))) uint32_t*)lds, 16, 0, 0);
}

// One block per row (x rows 0..4095, w rows 4096..12287):
// invnorm[row] = 1/||row||, rmax[row] = max|row| * invnorm. No atomics.
__global__ __launch_bounds__(256) void rownorm_kernel(
    const float* __restrict__ x, const float* __restrict__ w,
    float* __restrict__ invnorm, float* __restrict__ rmax) {
  const int row = blockIdx.x;
  const float* a = (row < M_ROWS) ? x + (size_t)row * D_COLS
                                  : w + (size_t)(row - M_ROWS) * D_COLS;
  const float4 v = ((const float4*)a)[threadIdx.x];
  float ss = v.x * v.x + v.y * v.y + v.z * v.z + v.w * v.w;
  float mx = fmaxf(fmaxf(fabsf(v.x), fabsf(v.y)), fmaxf(fabsf(v.z), fabsf(v.w)));
#pragma unroll
  for (int off = 32; off; off >>= 1) {
    ss += __shfl_down(ss, off, 64);
    mx = fmaxf(mx, __shfl_down(mx, off, 64));
  }
  __shared__ float s_ss[4], s_mx[4];
  const int wave = threadIdx.x >> 6, lane = threadIdx.x & 63;
  if (lane == 0) { s_ss[wave] = ss; s_mx[wave] = mx; }
  __syncthreads();
  if (threadIdx.x == 0) {
    float tss = (s_ss[0] + s_ss[1]) + (s_ss[2] + s_ss[3]);
    float tmx = fmaxf(fmaxf(s_mx[0], s_mx[1]), fmaxf(s_mx[2], s_mx[3]));
    float inv = 1.0f / fmaxf(sqrtf(tss), 1e-12f);
    invnorm[row] = inv;
    rmax[row] = tmx * inv;
  }
}

// Single block: scales[0] = max(rmax[0:4096]), scales[1] = max(rmax[4096:12288])
__global__ __launch_bounds__(1024) void scale_reduce_kernel(
    const float* __restrict__ rmax, float* __restrict__ scales) {
  const int t = threadIdx.x;
  float mx = 0.f, mw = 0.f;
  for (int i = t; i < M_ROWS; i += 1024) mx = fmaxf(mx, rmax[i]);
  for (int i = t; i < N_ROWS; i += 1024) mw = fmaxf(mw, rmax[M_ROWS + i]);
#pragma unroll
  for (int off = 32; off; off >>= 1) {
    mx = fmaxf(mx, __shfl_down(mx, off, 64));
    mw = fmaxf(mw, __shfl_down(mw, off, 64));
  }
  __shared__ float smx[16], smw[16];
  const int wave = t >> 6, lane = t & 63;
  if (lane == 0) { smx[wave] = mx; smw[wave] = mw; }
  __syncthreads();
  if (t == 0) {
    float a = 0.f, b = 0.f;
#pragma unroll
    for (int i = 0; i < 16; ++i) { a = fmaxf(a, smx[i]); b = fmaxf(b, smw[i]); }
    scales[0] = a;
    scales[1] = b;
  }
}

// ---------------------------------------------------------------------------
// Quantize + transpose into the blocked GEMM image via LDS (R9, unchanged).
// img (uint4 units): panel p (256 rows) base p*16384; entry (cc, rr) at
// cc*256 + rr, cc = K-16B-chunk 0..63, rr = row-in-panel 0..255.
// ---------------------------------------------------------------------------
__global__ __launch_bounds__(256) void quant_transpose_kernel(
    const float* __restrict__ a, const float* __restrict__ invnorm,
    const float* __restrict__ scale, uint4* __restrict__ img) {
  __shared__ uint4 T[128][16];
  const int t = threadIdx.x;
  const int g = blockIdx.x & 3;          // cc group (16 cc's)
  const int rh = (blockIdx.x >> 2) & 1;  // row half of panel
  const int p = blockIdx.x >> 3;         // panel
  const float s = 127.0f / scale[0];

  const int cc_l = t & 15;
  const int tr = t >> 4;
#pragma unroll
  for (int rc = 0; rc < 8; ++rc) {
    const int rl = rc * 16 + tr;
    const int r = p * 256 + rh * 128 + rl;
    const float f = invnorm[r] * s;
    const float4* src = (const float4*)(a + (size_t)r * D_COLS + (g * 16 + cc_l) * 16);
    unsigned pk[4];
#pragma unroll
    for (int q = 0; q < 4; ++q) {
      const float4 v = src[q];
      const int q0 = (int)rintf(v.x * f), q1 = (int)rintf(v.y * f);
      const int q2 = (int)rintf(v.z * f), q3 = (int)rintf(v.w * f);
      pk[q] = (unsigned)(q0 & 0xff) | ((unsigned)(q1 & 0xff) << 8) |
              ((unsigned)(q2 & 0xff) << 16) | ((unsigned)(q3 & 0xff) << 24);
    }
    T[rl][cc_l ^ (rl & 15)] = make_uint4(pk[0], pk[1], pk[2], pk[3]);
  }
  __syncthreads();

  const int cc_w = t >> 4;
  const int rw = t & 15;
  uint4* dst = img + (size_t)p * 16384 + (size_t)(g * 16 + cc_w) * 256 + rh * 128;
#pragma unroll
  for (int i = 0; i < 8; ++i) {
    const int rl = i * 16 + rw;
    dst[rl] = T[rl][cc_w ^ (rl & 15)];
  }
}

// ---------------------------------------------------------------------------
// int8 GEMM, 256x256 tile, 8 waves (wr=wid>>2, wc=wid&3), 8 K-tiles of
// BK=128B, 4 phases per K-tile, 16 MFMA per phase, ring-2 of 64KB LDS bufs.
//
// Blocked slabs: (panel P, kt) = 32KB at (P*8+kt)*32768, [ck 0..7][rr][16B].
// Buf (kt&1): A slab copy at +0, B at +32768.
//
// Phase (kt, f): kh=f>>1, qm=f&1.
//   reads: af[4] rows wr*128+qm*64.., ck kh*4+ko; even f also bf[4]
//   stage: f==0/1 issue 4 of kt+1's 8 gloads
//   f==3: vmcnt(0) (kt+1's loads, >=2 phases old -> ~free)
//   barrier; lgkmcnt(0); setprio(1); 16 MFMA; setprio(0); barrier
// Ledger: every phase drains lgkmcnt(0) before its trailing barrier, so
// when (kt,f0) stages into buf (kt+1)&1 == (kt-1)&1, all reads of kt-1
// (last at (kt-1,f3)) are long complete. Reads of buf kt follow the
// (kt-1,f3) vmcnt(0)+two barriers. Race-free.
// ---------------------------------------------------------------------------
__global__ __launch_bounds__(512) void gemm_i8_kernel(
    const char* __restrict__ qx, const char* __restrict__ qw,
    const float* __restrict__ sx, const float* __restrict__ sw,
    float* __restrict__ out) {
  __shared__ __align__(16) char L[131072];
  const int t = threadIdx.x;
  const int wave = t >> 6, lane = t & 63;
  const int wr = wave >> 2, wc = wave & 3;
  const int rl = lane & 15, ko = lane >> 4;

  i32x4 acc[8][4] = {};

#define ISSUE_PART(kt, part)                                                  \
  {                                                                           \
    const char* sa_ = qx + ((size_t)blockIdx.y * 8 + (kt)) * 32768;           \
    const char* sb_ = qw + ((size_t)blockIdx.x * 8 + (kt)) * 32768;           \
    char* d_ = L + ((kt) & 1) * 65536;                                        \
    _Pragma("unroll") for (int i_ = (part) * 2; i_ < (part) * 2 + 2; ++i_) {  \
      gload_lds16(sa_ + wave * 4096 + i_ * 1024 + lane * 16,                  \
                  d_ + wave * 4096 + i_ * 1024);                              \
      gload_lds16(sb_ + wave * 4096 + i_ * 1024 + lane * 16,                  \
                  d_ + 32768 + wave * 4096 + i_ * 1024);                      \
    }                                                                         \
  }

#define PHASE(kt, f)                                                          \
  {                                                                           \
    const char* Ab_ = L + ((kt) & 1) * 65536;                                 \
    const char* Bb_ = Ab_ + 32768;                                            \
    const int kh_ = (f) >> 1, qm_ = (f) & 1;                                  \
    i32x4 af_[4];                                                             \
    _Pragma("unroll") for (int m_ = 0; m_ < 4; ++m_)                          \
      af_[m_] = *(const i32x4*)(Ab_ +                                         \
          ((kh_ * 4 + ko) * 256 + wr * 128 + qm_ * 64 + m_ * 16 + rl) * 16);  \
    if ((f) % 2 == 0) {                                                       \
      _Pragma("unroll") for (int n_ = 0; n_ < 4; ++n_)                        \
        bf_[n_] = *(const i32x4*)(Bb_ +                                       \
            ((kh_ * 4 + ko) * 256 + wc * 64 + n_ * 16 + rl) * 16);            \
    }                                                                         \
    if ((kt) < 7 && (f) < 2) ISSUE_PART((kt) + 1, (f));                       \
    if ((f) == 3) asm volatile("s_waitcnt vmcnt(0)" ::: "memory");            \
    __builtin_amdgcn_s_barrier();                                             \
    asm volatile("s_waitcnt lgkmcnt(0)" ::: "memory");                        \
    __builtin_amdgcn_s_setprio(1);                                            \
    _Pragma("unroll") for (int m_ = 0; m_ < 4; ++m_)                          \
      _Pragma("unroll") for (int n_ = 0; n_ < 4; ++n_)                        \
        acc[qm_ * 4 + m_][n_] = __builtin_amdgcn_mfma_i32_16x16x64_i8(        \
            af_[m_], bf_[n_], acc[qm_ * 4 + m_][n_], 0, 0, 0);                \
    __builtin_amdgcn_s_setprio(0);                                            \
    __builtin_amdgcn_s_barrier();                                             \
  }

  // prologue: K-tile 0 fully staged, drained once
  ISSUE_PART(0, 0);
  ISSUE_PART(0, 1);
  asm volatile("s_waitcnt vmcnt(0)" ::: "memory");
  __builtin_amdgcn_s_barrier();

#pragma unroll 1
  for (int kt = 0; kt < 8; ++kt) {
    i32x4 bf_[4];
    PHASE(kt, 0);
    PHASE(kt, 1);
    PHASE(kt, 2);
    PHASE(kt, 3);
  }
#undef PHASE
#undef ISSUE_PART

  const float cs = sx[0] * sw[0] * (1.0f / 16129.0f);  // (sx/127)*(sw/127)
  const int rowBase = blockIdx.y * 256;
  const int colBase = blockIdx.x * 256;
#pragma unroll
  for (int m = 0; m < 8; ++m) {
    const int row = rowBase + wr * 128 + m * 16 + ko * 4;
#pragma unroll
    for (int n = 0; n < 4; ++n) {
      const int col = colBase + wc * 64 + n * 16 + rl;
#pragma unroll
      for (int j = 0; j < 4; ++j)
        out[(size_t)(row + j) * N_ROWS + col] = 1.0f - (float)acc[m][n][j] * cs;
    }
  }
}

extern "C" void kernel_launch(void* const* d_in, const int* in_sizes, int n_in,
                              void* d_out, int out_size, void* d_ws, size_t ws_size,
                              hipStream_t stream) {
  const float* x = (const float*)d_in[0];   // [4096, 1024]
  const float* w = (const float*)d_in[1];   // [8192, 1024]
  float* out = (float*)d_out;               // [4096, 8192]

  char* ws = (char*)d_ws;
  char* qx = ws;                                        // 4 MB blocked image
  char* qw = ws + (size_t)M_ROWS * D_COLS;              // 8 MB blocked image
  float* invnorm = (float*)(ws + (size_t)(M_ROWS + N_ROWS) * D_COLS);  // [12288]
  float* rmax = invnorm + (M_ROWS + N_ROWS);            // [12288]
  float* scales = rmax + (M_ROWS + N_ROWS);             // [0]=sx, [1]=sw

  rownorm_kernel<<<M_ROWS + N_ROWS, 256, 0, stream>>>(x, w, invnorm, rmax);
  scale_reduce_kernel<<<1, 1024, 0, stream>>>(rmax, scales);

  quant_transpose_kernel<<<M_ROWS / 256 * 8, 256, 0, stream>>>(
      x, invnorm, &scales[0], (uint4*)qx);
  quant_transpose_kernel<<<N_ROWS / 256 * 8, 256, 0, stream>>>(
      w, invnorm + M_ROWS, &scales[1], (uint4*)qw);

  dim3 grid(N_ROWS / 256, M_ROWS / 256);  // (32, 16) = 512 blocks
  gemm_i8_kernel<<<grid, 512, 0, stream>>>(qx, qw, &scales[0], &scales[1], out);
}